// Round 1
// baseline (281.839 us; speedup 1.0000x reference)
//
#include <hip/hip_runtime.h>

// SetNetwork: per-request MLP (64->256->256) + ragged sum-pool + head.
// B=2048, MAXR=512. bf16 MFMA for the per-request MLP, fp32 head.

typedef __bf16 bf16x8 __attribute__((ext_vector_type(8)));
typedef float f32x4 __attribute__((ext_vector_type(4)));

#define MFMA16(a, b, c) __builtin_amdgcn_mfma_f32_16x16x32_bf16((a), (b), (c), 0, 0, 0)

// ---------------------------------------------------------------------------
// K1: convert + transpose weights to bf16.  WinT[256][64] = W_in[64][256]^T,
//     We1T[256][256] = W_e1[256][256]^T.  Grid: 320 blocks x 256 threads.
// ---------------------------------------------------------------------------
__global__ __launch_bounds__(256) void convert_w(const float* __restrict__ Win,
                                                 const float* __restrict__ We1,
                                                 __bf16* __restrict__ WinT,
                                                 __bf16* __restrict__ We1T) {
  int t = blockIdx.x * 256 + threadIdx.x;
  if (t < 16384) {
    int nn = t >> 6, k = t & 63;
    WinT[t] = (__bf16)Win[k * 256 + nn];
  } else {
    int e = t - 16384;  // 0..65535
    int nn = e >> 8, k = e & 255;
    We1T[e] = (__bf16)We1[k * 256 + nn];
  }
}

// ---------------------------------------------------------------------------
// K2: per-batch ragged MLP + pool.  One block per batch (2048 blocks, 4 waves).
// Each wave owns a 64-column slice of the 256-wide hidden dims.
// Tile = 64 rows; rows >= n_req are zero-filled (relu(0)=0 -> no pool contrib).
// Column sums kept in registers across tiles -> deterministic, no atomics.
// ---------------------------------------------------------------------------
__global__ __launch_bounds__(256) void mlp_pool(const float* __restrict__ x_req,
                                                const int* __restrict__ n_req,
                                                const __bf16* __restrict__ WinT,
                                                const __bf16* __restrict__ We1T,
                                                float* __restrict__ pooled) {
  // A: x_req tile, bf16, stride 72 (144B = 9*16B: aligned, 2-way banks max)
  // H: layer-1 output, bf16, stride 264 (528B = 33*16B)
  __shared__ __align__(16) __bf16 A[64][72];
  __shared__ __align__(16) __bf16 H[64][264];

  const int b = blockIdx.x;
  const int n = n_req[b];
  const int ntiles = (n + 63) >> 6;
  const int tid = threadIdx.x;
  const int wid = tid >> 6;         // wave id 0..3 -> column slice wid*64
  const int lane = tid & 63;
  const int llo = lane & 15;
  const int lhi = lane >> 4;

  const f32x4 zero4 = {0.f, 0.f, 0.f, 0.f};
  float colsum[4] = {0.f, 0.f, 0.f, 0.f};  // col = wid*64 + nf*16 + llo

  if (ntiles > 0) {
    // Layer-1 B fragments: reused by every tile -> hoist into registers (32 VGPR).
    // B-frag layout: lane holds B[k = kk*32 + lhi*8 + j][col = n0 + llo], j=0..7,
    // i.e. WinT[col][k..k+8) contiguous 16B.
    bf16x8 bw1[4][2];
#pragma unroll
    for (int nf = 0; nf < 4; ++nf)
#pragma unroll
      for (int kk = 0; kk < 2; ++kk)
        bw1[nf][kk] = *(const bf16x8*)(WinT + (wid * 64 + nf * 16 + llo) * 64 +
                                       kk * 32 + lhi * 8);

    for (int t = 0; t < ntiles; ++t) {
      if (t > 0) __syncthreads();  // protect A/H overwrite vs prior tile reads

      // ---- stage x_req tile -> A (fp32 -> bf16), zero invalid rows ----
      const int valid = min(64, n - t * 64);
      const float* src = x_req + ((size_t)b * 512 + (size_t)t * 64) * 64;
#pragma unroll
      for (int i = 0; i < 4; ++i) {
        int flat = tid + i * 256;          // float4 id 0..1023
        int row = flat >> 4, c4 = flat & 15;
        float4 v = make_float4(0.f, 0.f, 0.f, 0.f);
        if (row < valid) v = ((const float4*)src)[row * 16 + c4];
        __bf16* dst = &A[row][c4 * 4];
        dst[0] = (__bf16)v.x; dst[1] = (__bf16)v.y;
        dst[2] = (__bf16)v.z; dst[3] = (__bf16)v.w;
      }
      __syncthreads();

      // ---- layer 1: [64x64] @ [64x256], relu -> H ----
      f32x4 acc1[4][4];
#pragma unroll
      for (int mi = 0; mi < 4; ++mi)
#pragma unroll
        for (int nf = 0; nf < 4; ++nf) acc1[mi][nf] = zero4;
#pragma unroll
      for (int kk = 0; kk < 2; ++kk) {
        bf16x8 af[4];
#pragma unroll
        for (int mi = 0; mi < 4; ++mi)
          af[mi] = *(const bf16x8*)&A[mi * 16 + llo][kk * 32 + lhi * 8];
#pragma unroll
        for (int nf = 0; nf < 4; ++nf)
#pragma unroll
          for (int mi = 0; mi < 4; ++mi)
            acc1[mi][nf] = MFMA16(af[mi], bw1[nf][kk], acc1[mi][nf]);
      }
      // D layout: row = (lane>>4)*4 + reg, col = lane&15 (m89-verified)
#pragma unroll
      for (int mi = 0; mi < 4; ++mi)
#pragma unroll
        for (int nf = 0; nf < 4; ++nf)
#pragma unroll
          for (int r = 0; r < 4; ++r)
            H[mi * 16 + lhi * 4 + r][wid * 64 + nf * 16 + llo] =
                (__bf16)fmaxf(acc1[mi][nf][r], 0.f);
      __syncthreads();

      // ---- layer 2: [64x256] @ [256x256], relu, accumulate column sums ----
      f32x4 acc2[4][4];
#pragma unroll
      for (int mi = 0; mi < 4; ++mi)
#pragma unroll
        for (int nf = 0; nf < 4; ++nf) acc2[mi][nf] = zero4;
#pragma unroll
      for (int kk = 0; kk < 8; ++kk) {
        bf16x8 af[4];
#pragma unroll
        for (int mi = 0; mi < 4; ++mi)
          af[mi] = *(const bf16x8*)&H[mi * 16 + llo][kk * 32 + lhi * 8];
#pragma unroll
        for (int nf = 0; nf < 4; ++nf) {
          bf16x8 bf_ = *(const bf16x8*)(We1T +
                          (size_t)(wid * 64 + nf * 16 + llo) * 256 +
                          kk * 32 + lhi * 8);
#pragma unroll
          for (int mi = 0; mi < 4; ++mi)
            acc2[mi][nf] = MFMA16(af[mi], bf_, acc2[mi][nf]);
        }
      }
#pragma unroll
      for (int mi = 0; mi < 4; ++mi)
#pragma unroll
        for (int nf = 0; nf < 4; ++nf)
#pragma unroll
          for (int r = 0; r < 4; ++r)
            colsum[nf] += fmaxf(acc2[mi][nf][r], 0.f);
    }
  }

  // reduce column sums across the 4 lane-groups, write pooled[b][0:256]
#pragma unroll
  for (int nf = 0; nf < 4; ++nf) {
    float v = colsum[nf];
    v += __shfl_xor(v, 16);
    v += __shfl_xor(v, 32);
    if (lane < 16) pooled[b * 256 + wid * 64 + nf * 16 + lane] = v;
  }
}

// ---------------------------------------------------------------------------
// K3: head.  req_embed = relu(pooled @ W_e2); x = [x_inst, req_embed];
//     h = relu(x @ W_c + b_c); out = h @ W_o + b_o.
// 16 batch rows per block, 128 blocks x 256 threads, fp32.
// ---------------------------------------------------------------------------
__global__ __launch_bounds__(256) void head_kernel(const float* __restrict__ x_inst,
                                                   const float* __restrict__ pooled,
                                                   const float* __restrict__ We2,
                                                   const float* __restrict__ Wc,
                                                   const float* __restrict__ bc,
                                                   const float* __restrict__ Wo,
                                                   const float* __restrict__ bo,
                                                   float* __restrict__ out) {
  __shared__ float P[16][256];
  __shared__ float XC[16][192];
  __shared__ float RED[4][16];
  const int tid = threadIdx.x;
  const int r0 = blockIdx.x * 16;

  // stage pooled rows (16x256) and x_inst rows (16x64 -> XC[:,0:64])
#pragma unroll
  for (int i = 0; i < 4; ++i) {
    int flat = tid + i * 256;
    int row = flat >> 6, c4 = flat & 63;
    float4 v = ((const float4*)(pooled + (size_t)(r0 + row) * 256))[c4];
    *(float4*)&P[row][c4 * 4] = v;
  }
  {
    int row = tid >> 4, c4 = tid & 15;
    float4 v = ((const float4*)(x_inst + (size_t)(r0 + row) * 64))[c4];
    *(float4*)&XC[row][c4 * 4] = v;
  }
  __syncthreads();

  // req_embed: 128 cols, threads split {row-half rh, col j}
  {
    const int rh = tid >> 7, j = tid & 127;
    float acc[8] = {0.f, 0.f, 0.f, 0.f, 0.f, 0.f, 0.f, 0.f};
    for (int k4 = 0; k4 < 64; ++k4) {
      float w0 = We2[(k4 * 4 + 0) * 128 + j];
      float w1 = We2[(k4 * 4 + 1) * 128 + j];
      float w2 = We2[(k4 * 4 + 2) * 128 + j];
      float w3 = We2[(k4 * 4 + 3) * 128 + j];
#pragma unroll
      for (int rr = 0; rr < 8; ++rr) {
        float4 pv = *(const float4*)&P[rh * 8 + rr][k4 * 4];
        acc[rr] += pv.x * w0 + pv.y * w1 + pv.z * w2 + pv.w * w3;
      }
    }
#pragma unroll
    for (int rr = 0; rr < 8; ++rr)
      XC[rh * 8 + rr][64 + j] = fmaxf(acc[rr], 0.f);
  }
  __syncthreads();

  // hidden (192->512) + output dot, 2 cols per thread
  float part[16];
#pragma unroll
  for (int r = 0; r < 16; ++r) part[r] = 0.f;
#pragma unroll
  for (int jj = 0; jj < 2; ++jj) {
    const int j = tid + jj * 256;
    float acc[16];
#pragma unroll
    for (int r = 0; r < 16; ++r) acc[r] = 0.f;
    for (int k4 = 0; k4 < 48; ++k4) {
      float w0 = Wc[(k4 * 4 + 0) * 512 + j];
      float w1 = Wc[(k4 * 4 + 1) * 512 + j];
      float w2 = Wc[(k4 * 4 + 2) * 512 + j];
      float w3 = Wc[(k4 * 4 + 3) * 512 + j];
#pragma unroll
      for (int r = 0; r < 16; ++r) {
        float4 xv = *(const float4*)&XC[r][k4 * 4];
        acc[r] += xv.x * w0 + xv.y * w1 + xv.z * w2 + xv.w * w3;
      }
    }
    const float bcv = bc[j], wov = Wo[j];
#pragma unroll
    for (int r = 0; r < 16; ++r)
      part[r] += fmaxf(acc[r] + bcv, 0.f) * wov;
  }
  // block reduction of part[16] over 256 threads
#pragma unroll
  for (int r = 0; r < 16; ++r) {
    part[r] += __shfl_xor(part[r], 1);
    part[r] += __shfl_xor(part[r], 2);
    part[r] += __shfl_xor(part[r], 4);
    part[r] += __shfl_xor(part[r], 8);
    part[r] += __shfl_xor(part[r], 16);
    part[r] += __shfl_xor(part[r], 32);
  }
  const int wid = tid >> 6, lane = tid & 63;
  if (lane == 0) {
#pragma unroll
    for (int r = 0; r < 16; ++r) RED[wid][r] = part[r];
  }
  __syncthreads();
  if (tid < 16)
    out[r0 + tid] = RED[0][tid] + RED[1][tid] + RED[2][tid] + RED[3][tid] + bo[0];
}

// ---------------------------------------------------------------------------
extern "C" void kernel_launch(void* const* d_in, const int* in_sizes, int n_in,
                              void* d_out, int out_size, void* d_ws, size_t ws_size,
                              hipStream_t stream) {
  const float* x_inst = (const float*)d_in[0];
  const float* x_req  = (const float*)d_in[1];
  const int*   n_req  = (const int*)d_in[2];
  const float* W_in   = (const float*)d_in[3];
  const float* W_e1   = (const float*)d_in[4];
  const float* W_e2   = (const float*)d_in[5];
  const float* W_c    = (const float*)d_in[6];
  const float* b_c    = (const float*)d_in[7];
  const float* W_o    = (const float*)d_in[8];
  const float* b_o    = (const float*)d_in[9];
  float* out = (float*)d_out;

  char* ws = (char*)d_ws;
  float*  pooled = (float*)ws;                               // 2048*256*4 = 2 MiB
  __bf16* WinT   = (__bf16*)(ws + 2 * 1024 * 1024);          // 32 KiB
  __bf16* We1T   = (__bf16*)(ws + 2 * 1024 * 1024 + 32 * 1024);  // 128 KiB

  convert_w<<<320, 256, 0, stream>>>(W_in, W_e1, WinT, We1T);
  mlp_pool<<<2048, 256, 0, stream>>>(x_req, n_req, WinT, We1T, pooled);
  head_kernel<<<128, 256, 0, stream>>>(x_inst, pooled, W_e2, W_c, b_c, W_o, b_o, out);
}